// Round 2
// baseline (407.720 us; speedup 1.0000x reference)
//
#include <hip/hip_runtime.h>
#include <hip/hip_bf16.h>
#include <math.h>

// Problem constants (fixed by reference)
#define BATCH 4096
#define LNUM  4
#define NEIGH 32
#define FEAT  256
#define EMB   128

#define B_TILE 4                 // batches per block
#define ROWS   (B_TILE * LNUM)   // 16 (b,l) rows per block
#define THREADS 512              // 8 waves

// ---------------------------------------------------------------------------
// Fully fused kernel, 8-wave blocks for 32 waves/CU (was 4-wave / 16 waves).
//  P1 gather+sum:  wave w -> batch (w>>1), layers (w&1)*2+{0,1}
//  P2 h-GEMM:      wave w -> layer (w&3), output cols (w>>2)*64+lane (M-split)
//  P3 scores:      wave w -> rows (w&3)*4..+3, cols (w>>2)*64+lane; partial
//                  tanh-dot reduced per wave into sc2[half][row]
//  P4a softmax+agg (512 threads == B_TILE*EMB elements)
//  P4b out GEMM:   wave w -> batch (w&3), cols (w>>2)*64+lane; partial norm
//                  combined via sNrm, both waves store their 64 outputs.
// Per-block L2 weight traffic unchanged vs 4-wave version (M-split, not
// row-duplicated): W 512KB, Ws1 256KB, Wt 256KB.
// LDS ~24.7KB -> 4 blocks/CU; launch_bounds(512,8) -> 32 waves/CU.
// ---------------------------------------------------------------------------
__global__ __launch_bounds__(THREADS, 8) void fused_liamne(
    const int* __restrict__ layers, const int* __restrict__ node_i,
    const int* __restrict__ neighs, const float* __restrict__ features,
    const float* __restrict__ layer_embs, const float* __restrict__ W,
    const float* __restrict__ Wt, const float* __restrict__ Ws1,
    const float* __restrict__ Ws2, float* __restrict__ out) {
  __shared__ float sS[ROWS][FEAT];    // 16 KB; rows 0..7 reused as sAgg in P4
  __shared__ float sH[ROWS][EMB];     // 8 KB
  __shared__ float sc2[2][ROWS];      // per-half partial scores
  __shared__ float sNrm[2][B_TILE];   // per-half partial ||.||^2

  int b0 = blockIdx.x * B_TILE;
  int tid = threadIdx.x;
  int w = tid >> 6;       // wave index 0..7
  int lane = tid & 63;

  // ---- Phase 1: gather + neighbor-sum into sS -----------------------------
  // Wave w owns batch b0+(w>>1), layers (w&1)*2 + {0,1}. 8 float4 loads in
  // flight per iteration (2 layers x 4 j).
  {
    int bi = w >> 1;
    int l0 = (w & 1) * 2;
    int nIdx[2];
#pragma unroll
    for (int l = 0; l < 2; ++l) {
      const int* nbr = neighs + ((size_t)(b0 + bi) * LNUM + l0 + l) * NEIGH;
      nIdx[l] = nbr[lane & 31];  // lanes 0..31 hold the 32 indices
    }
    const float4* f4 = (const float4*)features;
    float4 acc[2];
#pragma unroll
    for (int l = 0; l < 2; ++l) acc[l] = make_float4(0.f, 0.f, 0.f, 0.f);
#pragma unroll
    for (int jj = 0; jj < 8; ++jj) {       // fully unrolled: constant shfl
      float4 v[2][4];
#pragma unroll
      for (int l = 0; l < 2; ++l)
#pragma unroll
        for (int q = 0; q < 4; ++q) {
          int n = __shfl(nIdx[l], jj * 4 + q, 64);
          v[l][q] = f4[(size_t)n * (FEAT / 4) + lane];
        }
#pragma unroll
      for (int l = 0; l < 2; ++l)
#pragma unroll
        for (int q = 0; q < 4; ++q) {
          acc[l].x += v[l][q].x; acc[l].y += v[l][q].y;
          acc[l].z += v[l][q].z; acc[l].w += v[l][q].w;
        }
    }
#pragma unroll
    for (int l = 0; l < 2; ++l)
      ((float4*)sS[bi * LNUM + l0 + l])[lane] = acc[l];
  }
  __syncthreads();

  // ---- Phase 2: sH[lb*4+l][col] = sS[lb*4+l] @ W[l], col=(w>>2)*64+lane ---
  {
    int l = w & 3, mh = w >> 2;
    const float* Wl = W + (size_t)l * FEAT * EMB + mh * 64 + lane;
    float acc[B_TILE] = {};
    for (int k = 0; k < FEAT; k += 4) {
      float4 s[B_TILE];
#pragma unroll
      for (int lb = 0; lb < B_TILE; ++lb)
        s[lb] = *(const float4*)&sS[lb * LNUM + l][k];
#pragma unroll
      for (int kk = 0; kk < 4; ++kk) {
        float wv = Wl[(size_t)(k + kk) * EMB];
#pragma unroll
        for (int lb = 0; lb < B_TILE; ++lb)
          acc[lb] += ((const float*)&s[lb])[kk] * wv;
      }
    }
#pragma unroll
    for (int lb = 0; lb < B_TILE; ++lb)
      sH[lb * LNUM + l][mh * 64 + lane] = acc[lb];
  }
  __syncthreads();

  // ---- Phase 3: partial scores: rows (w&3)*4..+3, cols (w>>2)*64+lane -----
  {
    int rg = w & 3, mh = w >> 2;
    int col = mh * 64 + lane;
    float acc[4] = {};
    for (int k = 0; k < EMB; k += 4) {
      float4 h[4];
#pragma unroll
      for (int i = 0; i < 4; ++i)
        h[i] = *(const float4*)&sH[rg * 4 + i][k];
#pragma unroll
      for (int kk = 0; kk < 4; ++kk) {
        float wv = Ws1[(size_t)(k + kk) * EMB + col];
#pragma unroll
        for (int i = 0; i < 4; ++i)
          acc[i] += ((const float*)&h[i])[kk] * wv;
      }
    }
    float w2 = Ws2[col];
#pragma unroll
    for (int i = 0; i < 4; ++i) {
      float p = tanhf(acc[i]) * w2;
#pragma unroll
      for (int m = 1; m < 64; m <<= 1) p += __shfl_xor(p, m, 64);
      if (lane == 0) sc2[mh][rg * 4 + i] = p;
    }
  }
  __syncthreads();

  // ---- Phase 4a: softmax + attention-weighted agg into sAgg (= sS) -------
  float* sAgg = &sS[0][0];  // B_TILE x EMB overlays dead sS
  {
    int lb = tid >> 7, m = tid & 127;   // 512 threads == 512 elements
    float s0 = sc2[0][lb * 4 + 0] + sc2[1][lb * 4 + 0];
    float s1 = sc2[0][lb * 4 + 1] + sc2[1][lb * 4 + 1];
    float s2 = sc2[0][lb * 4 + 2] + sc2[1][lb * 4 + 2];
    float s3 = sc2[0][lb * 4 + 3] + sc2[1][lb * 4 + 3];
    float mx = fmaxf(fmaxf(s0, s1), fmaxf(s2, s3));
    float e0 = expf(s0 - mx), e1 = expf(s1 - mx);
    float e2 = expf(s2 - mx), e3 = expf(s3 - mx);
    float inv = 1.0f / (e0 + e1 + e2 + e3);
    float a = e0 * sH[lb * 4 + 0][m] + e1 * sH[lb * 4 + 1][m] +
              e2 * sH[lb * 4 + 2][m] + e3 * sH[lb * 4 + 3][m];
    sAgg[tid] = a * inv;
  }
  __syncthreads();

  // ---- Phase 4b: wave w: batch w&3, cols (w>>2)*64+lane -------------------
  {
    int lb = w & 3, mh = w >> 2;
    int col = mh * 64 + lane;
    float ax = 0.f;
    for (int k = 0; k < EMB; ++k)
      ax += sAgg[lb * EMB + k] * Wt[(size_t)k * EMB + col];
    int b = b0 + lb;
    int node = node_i[b];
    int lay = layers[b];
    ax += layer_embs[((size_t)node * LNUM + lay) * EMB + col];
    float ss = ax * ax;
#pragma unroll
    for (int m = 1; m < 64; m <<= 1) ss += __shfl_xor(ss, m, 64);
    if (lane == 0) sNrm[mh][lb] = ss;
    __syncthreads();
    float tot = sNrm[0][lb] + sNrm[1][lb];
    float inv = 1.0f / fmaxf(sqrtf(tot), 1e-12f);
    out[(size_t)b * EMB + col] = ax * inv;
  }
}

extern "C" void kernel_launch(void* const* d_in, const int* in_sizes, int n_in,
                              void* d_out, int out_size, void* d_ws,
                              size_t ws_size, hipStream_t stream) {
  const int* layers = (const int*)d_in[0];
  const int* node_i = (const int*)d_in[1];
  const int* neighs = (const int*)d_in[2];
  const float* features = (const float*)d_in[3];
  const float* layer_embs = (const float*)d_in[4];
  const float* neigh_emb_trans = (const float*)d_in[5];
  const float* trans_weights = (const float*)d_in[6];
  const float* trans_weights_s1 = (const float*)d_in[7];
  const float* trans_weights_s2 = (const float*)d_in[8];
  float* out = (float*)d_out;

  fused_liamne<<<dim3(BATCH / B_TILE), THREADS, 0, stream>>>(
      layers, node_i, neighs, features, layer_embs, neigh_emb_trans,
      trans_weights, trans_weights_s1, trans_weights_s2, out);
}